// Round 7
// baseline (88.961 us; speedup 1.0000x reference)
//
#include <hip/hip_runtime.h>

// Problem constants: B=4, N=256, E=512, fp32.
#define B_ 4
#define N_ 256
#define E_ 512

// ws layout (floats): QwT[256*256], Gpart[16][256*256]  (~4.25 MB total)

// ---------------------------------------------------------------------------
// prep_kernel: grid (4,4,17), block (16,16).  [unchanged — ~3.5 µs]
//  bz 0..15: split-K Gram partial; bz==16: Qw transpose.
// ---------------------------------------------------------------------------
__global__ __launch_bounds__(256) void prep_kernel(
    const float* __restrict__ X, const float* __restrict__ Qw,
    float* __restrict__ QwT, float* __restrict__ Gpart) {

    const int bx = blockIdx.x, by = blockIdx.y, bz = blockIdx.z;
    const int tx = threadIdx.x, ty = threadIdx.y;
    const int tid = ty * 16 + tx;

    if (bz == 16) {
        __shared__ float tt[64][68];
        const int r = tid >> 2, c0 = tid & 3;
#pragma unroll
        for (int cc = 0; cc < 4; ++cc) {
            const int c = (c0 + cc * 4) * 4;
            const float4 v = *(const float4*)&Qw[(by * 64 + r) * N_ + bx * 64 + c];
            tt[c + 0][r] = v.x; tt[c + 1][r] = v.y;
            tt[c + 2][r] = v.z; tt[c + 3][r] = v.w;
        }
        __syncthreads();
#pragma unroll
        for (int cc = 0; cc < 4; ++cc) {
            const int c = (c0 + cc * 4) * 4;
            const float4 v = *(const float4*)&tt[r][c];
            *(float4*)&QwT[(bx * 64 + r) * N_ + by * 64 + c] = v;
        }
        return;
    }

    const int b = bz >> 2, kq = bz & 3;
    const float* __restrict__ Xb = X + (size_t)b * N_ * E_;
    __shared__ float At[32][68];
    __shared__ float Bt[32][68];
    float acc[4][4] = {};
    const int r = tid >> 2, c0 = tid & 3;

    for (int k0 = kq * 128; k0 < kq * 128 + 128; k0 += 32) {
        {
            const float4 va = *(const float4*)&Xb[(size_t)(by * 64 + r) * E_ + k0 + c0 * 8];
            const float4 vb = *(const float4*)&Xb[(size_t)(by * 64 + r) * E_ + k0 + c0 * 8 + 4];
            At[c0*8+0][r] = va.x; At[c0*8+1][r] = va.y; At[c0*8+2][r] = va.z; At[c0*8+3][r] = va.w;
            At[c0*8+4][r] = vb.x; At[c0*8+5][r] = vb.y; At[c0*8+6][r] = vb.z; At[c0*8+7][r] = vb.w;
            const float4 wa = *(const float4*)&Xb[(size_t)(bx * 64 + r) * E_ + k0 + c0 * 8];
            const float4 wb = *(const float4*)&Xb[(size_t)(bx * 64 + r) * E_ + k0 + c0 * 8 + 4];
            Bt[c0*8+0][r] = wa.x; Bt[c0*8+1][r] = wa.y; Bt[c0*8+2][r] = wa.z; Bt[c0*8+3][r] = wa.w;
            Bt[c0*8+4][r] = wb.x; Bt[c0*8+5][r] = wb.y; Bt[c0*8+6][r] = wb.z; Bt[c0*8+7][r] = wb.w;
        }
        __syncthreads();
#pragma unroll
        for (int kk = 0; kk < 32; ++kk) {
            const float4 a  = *(const float4*)&At[kk][ty * 4];
            const float4 bb = *(const float4*)&Bt[kk][tx * 4];
            acc[0][0] += a.x*bb.x; acc[0][1] += a.x*bb.y; acc[0][2] += a.x*bb.z; acc[0][3] += a.x*bb.w;
            acc[1][0] += a.y*bb.x; acc[1][1] += a.y*bb.y; acc[1][2] += a.y*bb.z; acc[1][3] += a.y*bb.w;
            acc[2][0] += a.z*bb.x; acc[2][1] += a.z*bb.y; acc[2][2] += a.z*bb.z; acc[2][3] += a.z*bb.w;
            acc[3][0] += a.w*bb.x; acc[3][1] += a.w*bb.y; acc[3][2] += a.w*bb.z; acc[3][3] += a.w*bb.w;
        }
        __syncthreads();
    }
    float* gout = Gpart + ((size_t)(kq * 4 + b) * N_ + by * 64 + ty * 4) * N_ + bx * 64 + tx * 4;
#pragma unroll
    for (int qi = 0; qi < 4; ++qi)
        *(float4*)&gout[(size_t)qi * N_] =
            make_float4(acc[qi][0], acc[qi][1], acc[qi][2], acc[qi][3]);
}

__device__ __forceinline__ void fma4(float4& a, float c, const float4& v) {
    a.x += c * v.x; a.y += c * v.y; a.z += c * v.z; a.w += c * v.w;
}

// ---------------------------------------------------------------------------
// fused: ONE ROW per block (RPB=1).  grid 1024, block 256 (4 waves).
// 4 blocks/CU resident (16 waves/CU) -> L2 latency hidden by cross-block TLP.
// Blocks c, c+256, c+512, c+768 share a CU; i = (b&1)?255-j:j makes their
// spans (j, 255-j, j, 255-j) -> constant per-CU work.
// ---------------------------------------------------------------------------
__global__ __launch_bounds__(256) void fused_kernel(
    const float* __restrict__ X, const float* __restrict__ Kw,
    const float* __restrict__ QwT, const float* __restrict__ Gpart,
    float* __restrict__ out) {

    const int blk = blockIdx.x;          // 0..1023
    const int b   = blk >> 8;
    const int j   = blk & 255;
    const int i   = (b & 1) ? (255 - j) : j;

    const int tid  = threadIdx.x;
    const int lane = tid & 63, wid = tid >> 6;

    const float4* __restrict__ Xb4 = (const float4*)(X + (size_t)b * N_ * E_);
    const float4* __restrict__ Kw4 = (const float4*)Kw;     // row stride 64
    const float4* __restrict__ Qt4 = (const float4*)QwT;    // row stride 64

    __shared__ float  xi[E_];          // 2 KB
    __shared__ float  gv[N_];          // zero-padded beyond i
    __shared__ float  sv[N_];
    __shared__ float  tv[N_];
    __shared__ float4 sp[4][128];      // 8 KB partial-reduce buffer
    __shared__ float  avgv;
    __shared__ float  red[4];
    float* const spf = (float*)sp;     // spf[w*512 + idx]

    // ---- load x_i (128 float4 by threads 0..127); gv from Gpart (4 quarters)
    if (tid < 128) ((float4*)xi)[tid] = Xb4[(size_t)i * 128 + tid];
    {
        float s = 0.f;
#pragma unroll
        for (int q = 0; q < 4; ++q)
            s += Gpart[((size_t)(q * 4 + b) * N_ + i) * N_ + tid];
        gv[tid] = (tid <= i) ? s : 0.f;
    }
    __syncthreads();

    // reduction bound: multiple of 32, >= i+1, <= 256
    const int Mc  = (i + 32) & ~31;
    const int cnt = Mc >> 2;           // per-wave chunk, multiple of 8
    const int nb  = wid * cnt;

    // ---- Phase B: s[p] = sum_n gv[n] * Kw[n][p]   (wave-chunked n)
    {
        float4 a0 = {0,0,0,0};
        for (int t8 = 0; t8 < cnt; t8 += 8) {
            const int n0 = nb + t8;
#pragma unroll
            for (int u = 0; u < 8; ++u)
                fma4(a0, gv[n0 + u], Kw4[(size_t)(n0 + u) * 64 + lane]);
        }
        sp[wid][lane] = a0;
    }
    __syncthreads();
    sv[tid] = (tid <= i)
        ? (spf[0*512 + tid] + spf[1*512 + tid] + spf[2*512 + tid] + spf[3*512 + tid])
        : 0.f;
    __syncthreads();

    // ---- Phase C: t[n] = sum_p sv[p] * QwT[p][n]   (wave-chunked p)
    {
        float4 a0 = {0,0,0,0};
        for (int t8 = 0; t8 < cnt; t8 += 8) {
            const int p0 = nb + t8;
#pragma unroll
            for (int u = 0; u < 8; ++u)
                fma4(a0, sv[p0 + u], Qt4[(size_t)(p0 + u) * 64 + lane]);
        }
        sp[wid][lane] = a0;
    }
    __syncthreads();
    tv[tid] = (tid <= i)
        ? (spf[0*512 + tid] + spf[1*512 + tid] + spf[2*512 + tid] + spf[3*512 + tid])
        : 0.f;
    __syncthreads();

    // ---- avg = sum_n tv[n] * gv[n]   (both zero-padded)
    {
        float v = tv[tid] * gv[tid];
#pragma unroll
        for (int off = 32; off > 0; off >>= 1)
            v += __shfl_xor(v, off, 64);
        if (lane == 0) red[wid] = v;
        __syncthreads();
        if (tid == 0) avgv = red[0] + red[1] + red[2] + red[3];
    }
    __syncthreads();

    // ---- Phase D: fit[m] = sum_n tv[n] * X[n][m]   (wave-chunked n)
    {
        float4 f0 = {0,0,0,0}, f1 = {0,0,0,0};
        for (int t8 = 0; t8 < cnt; t8 += 8) {
            const int n0 = nb + t8;
#pragma unroll
            for (int u = 0; u < 8; ++u) {
                const float tc = tv[n0 + u];
                fma4(f0, tc, Xb4[(size_t)(n0 + u) * 128 + lane]);
                fma4(f1, tc, Xb4[(size_t)(n0 + u) * 128 + 64 + lane]);
            }
        }
        sp[wid][lane]      = f0;       // m = 0..255 slice
        sp[wid][64 + lane] = f1;       // m = 256..511 slice
    }
    __syncthreads();
    {
        const float a0 = avgv;
        float* const o = out + ((size_t)b * N_ + i) * E_;
        const float fit0 = spf[0*512 + tid]       + spf[1*512 + tid]
                         + spf[2*512 + tid]       + spf[3*512 + tid];
        const float fit1 = spf[0*512 + 256 + tid] + spf[1*512 + 256 + tid]
                         + spf[2*512 + 256 + tid] + spf[3*512 + 256 + tid];
        o[tid]       = xi[tid]       * (1.f + fit0 - a0);
        o[tid + 256] = xi[tid + 256] * (1.f + fit1 - a0);
    }
}

// ---------------------------------------------------------------------------
extern "C" void kernel_launch(void* const* d_in, const int* in_sizes, int n_in,
                              void* d_out, int out_size, void* d_ws, size_t ws_size,
                              hipStream_t stream) {
    const float* X  = (const float*)d_in[0];   // (B,N,E)
    const float* Qw = (const float*)d_in[1];   // (N,N)
    const float* Kw = (const float*)d_in[2];   // (N,N)
    float* out = (float*)d_out;                // (B,N,E)

    float* QwT   = (float*)d_ws;               // 256 KB
    float* Gpart = QwT + (size_t)N_ * N_;      // 16 * 256 KB = 4 MB

    prep_kernel<<<dim3(4, 4, 17), dim3(16, 16), 0, stream>>>(X, Qw, QwT, Gpart);
    fused_kernel<<<B_ * N_, 256, 0, stream>>>(X, Kw, QwT, Gpart, out);
}

// Round 8
// 82.598 us; speedup vs baseline: 1.0770x; 1.0770x over previous
//
#include <hip/hip_runtime.h>

// Problem constants: B=4, N=256, E=512, fp32.
#define B_ 4
#define N_ 256
#define E_ 512

// ws layout (floats): QwT[256*256], Gpart[16][256*256]  (~4.25 MB total)

// ---------------------------------------------------------------------------
// prep_kernel: grid (4,4,17), block (16,16).  [unchanged]
//  bz 0..15: split-K Gram partial; bz==16: Qw transpose.
// ---------------------------------------------------------------------------
__global__ __launch_bounds__(256) void prep_kernel(
    const float* __restrict__ X, const float* __restrict__ Qw,
    float* __restrict__ QwT, float* __restrict__ Gpart) {

    const int bx = blockIdx.x, by = blockIdx.y, bz = blockIdx.z;
    const int tx = threadIdx.x, ty = threadIdx.y;
    const int tid = ty * 16 + tx;

    if (bz == 16) {
        __shared__ float tt[64][68];
        const int r = tid >> 2, c0 = tid & 3;
#pragma unroll
        for (int cc = 0; cc < 4; ++cc) {
            const int c = (c0 + cc * 4) * 4;
            const float4 v = *(const float4*)&Qw[(by * 64 + r) * N_ + bx * 64 + c];
            tt[c + 0][r] = v.x; tt[c + 1][r] = v.y;
            tt[c + 2][r] = v.z; tt[c + 3][r] = v.w;
        }
        __syncthreads();
#pragma unroll
        for (int cc = 0; cc < 4; ++cc) {
            const int c = (c0 + cc * 4) * 4;
            const float4 v = *(const float4*)&tt[r][c];
            *(float4*)&QwT[(bx * 64 + r) * N_ + by * 64 + c] = v;
        }
        return;
    }

    const int b = bz >> 2, kq = bz & 3;
    const float* __restrict__ Xb = X + (size_t)b * N_ * E_;
    __shared__ float At[32][68];
    __shared__ float Bt[32][68];
    float acc[4][4] = {};
    const int r = tid >> 2, c0 = tid & 3;

    for (int k0 = kq * 128; k0 < kq * 128 + 128; k0 += 32) {
        {
            const float4 va = *(const float4*)&Xb[(size_t)(by * 64 + r) * E_ + k0 + c0 * 8];
            const float4 vb = *(const float4*)&Xb[(size_t)(by * 64 + r) * E_ + k0 + c0 * 8 + 4];
            At[c0*8+0][r] = va.x; At[c0*8+1][r] = va.y; At[c0*8+2][r] = va.z; At[c0*8+3][r] = va.w;
            At[c0*8+4][r] = vb.x; At[c0*8+5][r] = vb.y; At[c0*8+6][r] = vb.z; At[c0*8+7][r] = vb.w;
            const float4 wa = *(const float4*)&Xb[(size_t)(bx * 64 + r) * E_ + k0 + c0 * 8];
            const float4 wb = *(const float4*)&Xb[(size_t)(bx * 64 + r) * E_ + k0 + c0 * 8 + 4];
            Bt[c0*8+0][r] = wa.x; Bt[c0*8+1][r] = wa.y; Bt[c0*8+2][r] = wa.z; Bt[c0*8+3][r] = wa.w;
            Bt[c0*8+4][r] = wb.x; Bt[c0*8+5][r] = wb.y; Bt[c0*8+6][r] = wb.z; Bt[c0*8+7][r] = wb.w;
        }
        __syncthreads();
#pragma unroll
        for (int kk = 0; kk < 32; ++kk) {
            const float4 a  = *(const float4*)&At[kk][ty * 4];
            const float4 bb = *(const float4*)&Bt[kk][tx * 4];
            acc[0][0] += a.x*bb.x; acc[0][1] += a.x*bb.y; acc[0][2] += a.x*bb.z; acc[0][3] += a.x*bb.w;
            acc[1][0] += a.y*bb.x; acc[1][1] += a.y*bb.y; acc[1][2] += a.y*bb.z; acc[1][3] += a.y*bb.w;
            acc[2][0] += a.z*bb.x; acc[2][1] += a.z*bb.y; acc[2][2] += a.z*bb.z; acc[2][3] += a.z*bb.w;
            acc[3][0] += a.w*bb.x; acc[3][1] += a.w*bb.y; acc[3][2] += a.w*bb.z; acc[3][3] += a.w*bb.w;
        }
        __syncthreads();
    }
    float* gout = Gpart + ((size_t)(kq * 4 + b) * N_ + by * 64 + ty * 4) * N_ + bx * 64 + tx * 4;
#pragma unroll
    for (int qi = 0; qi < 4; ++qi)
        *(float4*)&gout[(size_t)qi * N_] =
            make_float4(acc[qi][0], acc[qi][1], acc[qi][2], acc[qi][3]);
}

__device__ __forceinline__ void fma4(float4& a, float c, const float4& v) {
    a.x += c * v.x; a.y += c * v.y; a.z += c * v.z; a.w += c * v.w;
}

// ---------------------------------------------------------------------------
// fused: RPB=4 complementary rows {2j, 2j+1, 254-2j, 255-2j} per block.
// grid 256 (B * N/4), block 512 (8 waves). Waves split the n/p range 8-way;
// each loaded panel vector feeds 4 rows (16-32 FMA per load -> latency
// covered by VALU). Loop bound Mc ~ 255-2j (bounded imbalance, ~2x less
// traffic than RPB=2).
// ---------------------------------------------------------------------------
__global__ __launch_bounds__(512) void fused_kernel(
    const float* __restrict__ X, const float* __restrict__ Kw,
    const float* __restrict__ QwT, const float* __restrict__ Gpart,
    float* __restrict__ out) {

    const int blk = blockIdx.x;          // 0..255
    const int b   = blk >> 6;
    const int j   = blk & 63;
    int irow[4];
    irow[0] = 2 * j;     irow[1] = 2 * j + 1;
    irow[2] = 254 - 2*j; irow[3] = 255 - 2*j;
    const int maxi = irow[3] > irow[1] ? irow[3] : irow[1];   // = 255-2j

    const int tid  = threadIdx.x;        // 0..511
    const int lane = tid & 63, wid = tid >> 6;

    const float4* __restrict__ Xb4 = (const float4*)(X + (size_t)b * N_ * E_);
    const float4* __restrict__ Kw4 = (const float4*)Kw;     // row stride 64
    const float4* __restrict__ Qt4 = (const float4*)QwT;    // row stride 64

    __shared__ float  xi[4][E_];         // 8 KB
    __shared__ float  gT[N_][4];         // 4 KB  [n][row], zero-padded
    __shared__ float  sT[N_][4];         // 4 KB
    __shared__ float  tT[N_][4];         // 4 KB
    __shared__ float4 sp4[2048];         // 32 KB reduce buffer (B/C/D union)
    __shared__ float  avgv[4];
    __shared__ float  red[4][4];
    float* const spf = (float*)sp4;

    // ---- prologue: xi rows (512 float4 by 512 threads); gT from Gpart
    {
        const int r = tid >> 7, c = tid & 127;
        ((float4*)xi[r])[c] = Xb4[(size_t)irow[r] * 128 + c];
    }
    if (tid < N_) {
#pragma unroll
        for (int r = 0; r < 4; ++r) {
            float s = 0.f;
#pragma unroll
            for (int q = 0; q < 4; ++q)
                s += Gpart[((size_t)(q * 4 + b) * N_ + irow[r]) * N_ + tid];
            gT[tid][r] = (tid <= irow[r]) ? s : 0.f;
        }
    }
    __syncthreads();

    // loop bound: multiple of 32, >= maxi+1
    const int Mc  = (maxi + 32) & ~31;
    const int cnt = Mc >> 3;             // per-wave n-chunk, multiple of 4
    const int nb  = wid * cnt;

    // ---- Phase B: s[p][r] = sum_n gT[n][r] * Kw[n][p]   (waves split n)
    {
        float4 a[4] = {{0,0,0,0},{0,0,0,0},{0,0,0,0},{0,0,0,0}};
        for (int t4 = 0; t4 < cnt; t4 += 4) {
#pragma unroll
            for (int u = 0; u < 4; ++u) {
                const int n = nb + t4 + u;
                const float4 kv = Kw4[(size_t)n * 64 + lane];
                const float4 gp = *(const float4*)&gT[n][0];
                fma4(a[0], gp.x, kv); fma4(a[1], gp.y, kv);
                fma4(a[2], gp.z, kv); fma4(a[3], gp.w, kv);
            }
        }
#pragma unroll
        for (int r = 0; r < 4; ++r)
            sp4[(wid * 4 + r) * 64 + lane] = a[r];
    }
    __syncthreads();
    {
        const int p = tid & 255, rbase = (tid >> 8) * 2;
#pragma unroll
        for (int rr = 0; rr < 2; ++rr) {
            const int r = rbase + rr;
            float v = 0.f;
#pragma unroll
            for (int w = 0; w < 8; ++w)
                v += spf[(w * 4 + r) * 256 + p];
            sT[p][r] = (p <= irow[r]) ? v : 0.f;
        }
    }
    __syncthreads();

    // ---- Phase C: t[n][r] = sum_p sT[p][r] * QwT[p][n]   (waves split p)
    {
        float4 a[4] = {{0,0,0,0},{0,0,0,0},{0,0,0,0},{0,0,0,0}};
        for (int t4 = 0; t4 < cnt; t4 += 4) {
#pragma unroll
            for (int u = 0; u < 4; ++u) {
                const int p = nb + t4 + u;
                const float4 qv = Qt4[(size_t)p * 64 + lane];
                const float4 sv = *(const float4*)&sT[p][0];
                fma4(a[0], sv.x, qv); fma4(a[1], sv.y, qv);
                fma4(a[2], sv.z, qv); fma4(a[3], sv.w, qv);
            }
        }
#pragma unroll
        for (int r = 0; r < 4; ++r)
            sp4[(wid * 4 + r) * 64 + lane] = a[r];
    }
    __syncthreads();
    {
        const int p = tid & 255, rbase = (tid >> 8) * 2;
#pragma unroll
        for (int rr = 0; rr < 2; ++rr) {
            const int r = rbase + rr;
            float v = 0.f;
#pragma unroll
            for (int w = 0; w < 8; ++w)
                v += spf[(w * 4 + r) * 256 + p];
            tT[p][r] = (p <= irow[r]) ? v : 0.f;
        }
    }
    __syncthreads();

    // ---- avg[r] = sum_n tT[n][r] * gT[n][r]   (tid<256, 4 chains)
    if (tid < N_) {
        float v0 = tT[tid][0] * gT[tid][0];
        float v1 = tT[tid][1] * gT[tid][1];
        float v2 = tT[tid][2] * gT[tid][2];
        float v3 = tT[tid][3] * gT[tid][3];
#pragma unroll
        for (int off = 32; off > 0; off >>= 1) {
            v0 += __shfl_xor(v0, off, 64);
            v1 += __shfl_xor(v1, off, 64);
            v2 += __shfl_xor(v2, off, 64);
            v3 += __shfl_xor(v3, off, 64);
        }
        if (lane == 0) {
            red[wid][0] = v0; red[wid][1] = v1;
            red[wid][2] = v2; red[wid][3] = v3;
        }
    }
    __syncthreads();
    if (tid == 0) {
#pragma unroll
        for (int r = 0; r < 4; ++r)
            avgv[r] = red[0][r] + red[1][r] + red[2][r] + red[3][r];
    }
    __syncthreads();

    // ---- Phase D: fit[r][m] = sum_n tT[n][r] * X[n][m]   (waves split n)
    float4 f[4][2] = {{{0,0,0,0},{0,0,0,0}},{{0,0,0,0},{0,0,0,0}},
                      {{0,0,0,0},{0,0,0,0}},{{0,0,0,0},{0,0,0,0}}};
    {
        for (int t2 = 0; t2 < cnt; t2 += 2) {
#pragma unroll
            for (int u = 0; u < 2; ++u) {
                const int n = nb + t2 + u;
                const float4 xa = Xb4[(size_t)n * 128 + lane];
                const float4 xb = Xb4[(size_t)n * 128 + 64 + lane];
                const float4 tv = *(const float4*)&tT[n][0];
                fma4(f[0][0], tv.x, xa); fma4(f[0][1], tv.x, xb);
                fma4(f[1][0], tv.y, xa); fma4(f[1][1], tv.y, xb);
                fma4(f[2][0], tv.z, xa); fma4(f[2][1], tv.z, xb);
                fma4(f[3][0], tv.w, xa); fma4(f[3][1], tv.w, xb);
            }
        }
    }
    // two reduce/store rounds of 2 rows each (sp4 reused: 8 waves x 2 rows x 128)
#pragma unroll
    for (int h = 0; h < 2; ++h) {
        __syncthreads();   // sp4 free (prev consumers done)
#pragma unroll
        for (int rr = 0; rr < 2; ++rr) {
            sp4[(wid * 2 + rr) * 128 + lane]      = f[2 * h + rr][0];
            sp4[(wid * 2 + rr) * 128 + 64 + lane] = f[2 * h + rr][1];
        }
        __syncthreads();
#pragma unroll
        for (int rr = 0; rr < 2; ++rr) {
            const int r = 2 * h + rr;
            float fit = 0.f;
#pragma unroll
            for (int w = 0; w < 8; ++w)
                fit += spf[(w * 2 + rr) * 512 + tid];
            float* const o = out + ((size_t)b * N_ + irow[r]) * E_;
            o[tid] = xi[r][tid] * (1.f + fit - avgv[r]);
        }
    }
}

// ---------------------------------------------------------------------------
extern "C" void kernel_launch(void* const* d_in, const int* in_sizes, int n_in,
                              void* d_out, int out_size, void* d_ws, size_t ws_size,
                              hipStream_t stream) {
    const float* X  = (const float*)d_in[0];   // (B,N,E)
    const float* Qw = (const float*)d_in[1];   // (N,N)
    const float* Kw = (const float*)d_in[2];   // (N,N)
    float* out = (float*)d_out;                // (B,N,E)

    float* QwT   = (float*)d_ws;               // 256 KB
    float* Gpart = QwT + (size_t)N_ * N_;      // 16 * 256 KB = 4 MB

    prep_kernel<<<dim3(4, 4, 17), dim3(16, 16), 0, stream>>>(X, Qw, QwT, Gpart);
    fused_kernel<<<B_ * (N_ / 4), 512, 0, stream>>>(X, Kw, QwT, Gpart, out);
}